// Round 8
// baseline (191.984 us; speedup 1.0000x reference)
//
#include <hip/hip_runtime.h>

#define BB 4
#define CC 128
#define NN 4096

typedef float f32x4 __attribute__((ext_vector_type(4)));
typedef __bf16 bf16x8 __attribute__((ext_vector_type(8)));

#define MFMA16(A, B, C) __builtin_amdgcn_mfma_f32_16x16x32_bf16((A), (B), (C), 0, 0, 0)

typedef __attribute__((address_space(3))) void lds_void;
typedef __attribute__((address_space(1))) void glob_void;
#define GLD16(g, l) __builtin_amdgcn_global_load_lds((const glob_void*)(g), (lds_void*)(l), 16, 0, 0)

// f(row): swizzle bits for 16B chunks within a 256B K row (16 chunks)
__device__ __forceinline__ int fK(int r) { return (r & 3) | (((r >> 3) & 1) << 2); }

// ---------------------------------------------------------------------------
// K0: one-shot weight prepack -> bf16 A-fragments, frag order
// [mat(4)][p(8)][ks(4)][lane(64)] x bf16x8. log2e folded into Wq/bq.
// (unchanged from R7)
// ---------------------------------------------------------------------------
__global__ __launch_bounds__(256)
void pack_w(const float* __restrict__ Wq, const float* __restrict__ bq,
            const float* __restrict__ Wk, const float* __restrict__ bk,
            const float* __restrict__ Wv, const float* __restrict__ bv,
            const float* __restrict__ Wo, const float* __restrict__ bo,
            __bf16* __restrict__ Wpk, float* __restrict__ bpk)
{
    const int mat = blockIdx.x >> 3;
    const int p   = blockIdx.x & 7;
    const int tid = threadIdx.x;
    const int ks  = tid >> 6;
    const int lane = tid & 63;
    const int col = lane & 15;
    const int quad = lane >> 4;

    const float LOG2E = 1.44269504088896340736f;
    const float* W = (mat == 0) ? Wq : (mat == 1) ? Wk : (mat == 2) ? Wv : Wo;
    const float* bsrc = (mat == 0) ? bq : (mat == 1) ? bk : (mat == 2) ? bv : bo;
    const float scale = (mat == 0) ? LOG2E : 1.0f;

    const float* wr = W + (size_t)(p * 16 + col) * CC + ks * 32 + quad * 8;
    float4 f0 = *(const float4*)wr;
    float4 f1 = *(const float4*)(wr + 4);
    bf16x8 a;
    a[0]=(__bf16)(f0.x*scale); a[1]=(__bf16)(f0.y*scale);
    a[2]=(__bf16)(f0.z*scale); a[3]=(__bf16)(f0.w*scale);
    a[4]=(__bf16)(f1.x*scale); a[5]=(__bf16)(f1.y*scale);
    a[6]=(__bf16)(f1.z*scale); a[7]=(__bf16)(f1.w*scale);
    *(bf16x8*)&Wpk[(((size_t)(mat * 8 + p) * 4 + ks) * 64 + lane) * 8] = a;

    if (p == 0 && tid < 128) bpk[mat * 128 + tid] = bsrc[tid] * scale;
}

// ---------------------------------------------------------------------------
// K1: QKV projection (unchanged from R7). 512-thr blocks, 32-n tiles, grid 512.
// ---------------------------------------------------------------------------
__global__ __launch_bounds__(512, 2)
void qkv_gemm(const float* __restrict__ x,
              const __bf16* __restrict__ Wpk, const float* __restrict__ bpk,
              __bf16* __restrict__ Qt, __bf16* __restrict__ Kt,
              __bf16* __restrict__ Vblk)
{
    const int b    = blockIdx.y;
    const int n0   = blockIdx.x * 32;
    const int tid  = threadIdx.x;
    const int lane = tid & 63;
    const int wv   = __builtin_amdgcn_readfirstlane(tid >> 6); // 0..7
    const int col  = lane & 15;
    const int quad = lane >> 4;

    __shared__ __bf16 xs[32 * 144];   // [n][c] bf16
    __shared__ __bf16 vs[128 * 32];   // V bounce [c][n]

    {
        const int n  = tid & 31;
        const int c0 = tid >> 5;               // 0..15
        const float* xb = x + ((size_t)b * CC) * NN + n0 + n;
#pragma unroll
        for (int i = 0; i < 4; i++) {
            int c = (c0 + i * 16) * 2;
            float v0 = xb[(size_t)c * NN];
            float v1 = xb[(size_t)(c + 1) * NN];
            union { __bf16 h[2]; unsigned u; } pk;
            pk.h[0] = (__bf16)v0; pk.h[1] = (__bf16)v1;
            *(unsigned*)&xs[n * 144 + c] = pk.u;
        }
    }
    __syncthreads();

    bf16x8 Bf[2][4];
#pragma unroll
    for (int ng = 0; ng < 2; ng++)
#pragma unroll
        for (int ks = 0; ks < 4; ks++)
            Bf[ng][ks] = *(const bf16x8*)&xs[(ng * 16 + col) * 144 + ks * 32 + quad * 8];

#pragma unroll 1
    for (int mat = 0; mat < 3; mat++) {           // 0=Q 1=K 2=V
        const int pg = wv;
        const int o0 = pg * 16;

        bf16x8 Af[4];
#pragma unroll
        for (int ks = 0; ks < 4; ks++)
            Af[ks] = *(const bf16x8*)&Wpk[(((size_t)(mat * 8 + pg) * 4 + ks) * 64 + lane) * 8];

        f32x4 D[2];
#pragma unroll
        for (int ng = 0; ng < 2; ng++) D[ng] = (f32x4){0.f, 0.f, 0.f, 0.f};
#pragma unroll
        for (int ks = 0; ks < 4; ks++)
#pragma unroll
            for (int ng = 0; ng < 2; ng++)
                D[ng] = MFMA16(Af[ks], Bf[ng][ks], D[ng]);

        float4 bias = *(const float4*)(bpk + mat * 128 + o0 + quad * 4);

#pragma unroll
        for (int ng = 0; ng < 2; ng++) {
            const int n = ng * 16 + col;              // tile-local 0..31
            float v[4];
#pragma unroll
            for (int r = 0; r < 4; r++)
                v[r] = D[ng][r] + ((const float*)&bias)[r];
            if (mat == 0) {
                union { __bf16 h[4]; uint2 u; } pk;
                for (int r = 0; r < 4; r++) pk.h[r] = (__bf16)v[r];
                *(uint2*)&Qt[((size_t)b * NN + n0 + n) * CC + o0 + quad * 4] = pk.u;
            } else if (mat == 1) {
                const int rin = ((n0 & 32) + n) & 63;       // row within 64-key tile
                const int chunk = ((o0 + quad * 4) >> 3) ^ fK(rin);
                union { __bf16 h[4]; uint2 u; } pk;
                for (int r = 0; r < 4; r++) pk.h[r] = (__bf16)v[r];
                *(uint2*)&Kt[((size_t)b * NN + n0 + n) * CC + chunk * 8 + (quad & 1) * 4] = pk.u;
            } else {
#pragma unroll
                for (int r = 0; r < 4; r++)
                    vs[(o0 + quad * 4 + r) * 32 + n] = (__bf16)v[r];
            }
        }
    }
    __syncthreads();

    {
        __bf16* vd = Vblk + (((size_t)b * 64 + (n0 >> 6)) * CC) * 64;
        const int chbase = (n0 & 32) >> 3;            // 0 or 4
        int idx = tid;                                // 0..511 = 128 c x 4 chunks
        int c = idx >> 2, chl = idx & 3;
        bf16x8 v = *(const bf16x8*)&vs[c * 32 + chl * 8];
        *(bf16x8*)&vd[c * 64 + (((chbase + chl) ^ (c & 7)) * 8)] = v;
    }
}

// ---------------------------------------------------------------------------
// K2: flash attention. Single-buffered K/V LDS (34.8 KB) -> 4 blocks/CU
// (launch_bounds(256,4)), grid 1024 = b(4) x jlow(2) [XCD-pinned] x jh(4) x
// it(32). 8-way j-split, 8 tiles/block. Epilogue: bf16 LDS bounce ->
// fully-coalesced 32 KB plane store to Opart[b][js][it][c][128].
// ---------------------------------------------------------------------------
__global__ __launch_bounds__(256, 4)
void flash_attn(const __bf16* __restrict__ Qt, const __bf16* __restrict__ Kt,
                const __bf16* __restrict__ Vblk,
                __bf16* __restrict__ Opart, float* __restrict__ Lpart)
{
    const int blk = blockIdx.x;
    const int b   = blk & 3;                  // pinned per XCD
    const int jlo = (blk >> 2) & 1;           // pinned per XCD
    const int rr  = blk >> 3;                 // 0..127
    const int js  = ((rr & 3) << 1) | jlo;    // 0..7
    const int it  = rr >> 2;                  // 0..31
    const int i0  = it * 128;

    const int tid  = threadIdx.x;
    const int lane = tid & 63;
    const int iw   = __builtin_amdgcn_readfirstlane(tid >> 6); // 0..3
    const int col  = lane & 15;
    const int quad = lane >> 4;

    // single buffer: K 16384 B + V 18432 B (V rows 128..143 = ones/zeros)
    __shared__ __align__(16) char smem[34816];
    char* Kbytes = smem;
    char* Vbytes = smem + 16384;
    __bf16* Vh = (__bf16*)Vbytes;

    // ones/zeros rows (persist: GLD16 only writes V rows 0..127)
#pragma unroll
    for (int e = 0; e < 4; e++) {
        int k = e * 256 + tid;                 // 0..1023
        Vh[8192 + k] = (__bf16)((k < 64) ? 1.0f : 0.0f);
    }

    const __bf16* Qb = Qt + (size_t)b * NN * CC;
    const char*   Ks = (const char*)(Kt + (size_t)b * NN * CC);
    const char*   Vs = (const char*)(Vblk + ((size_t)b * 64 * CC) * 64);

    const int ibase = i0 + iw * 32;

    // Q fragments (B operand): n=col=query, k=quad*8+e
    bf16x8 qf[2][4];
#pragma unroll
    for (int ig = 0; ig < 2; ig++)
#pragma unroll
        for (int ks = 0; ks < 4; ks++)
            qf[ig][ks] = *(const bf16x8*)(Qb + (size_t)(ibase + ig * 16 + col) * CC
                                             + ks * 32 + quad * 8);

    // precomputed swizzled LDS byte addrs
    const int perm = ((col & 12) << 1) | (col & 3);
    const int fR   = fK(perm);
    int kaddr[4][4];
    const int joff[4] = {0, 4, 32, 36};
#pragma unroll
    for (int jg = 0; jg < 4; jg++)
#pragma unroll
        for (int ks = 0; ks < 4; ks++)
            kaddr[jg][ks] = (perm + joff[jg]) * 256 + (((ks * 4 + quad) ^ fR) * 16);
    int vaddr[8][2], oaddr[2];
#pragma unroll
    for (int cg = 0; cg < 8; cg++)
#pragma unroll
        for (int t = 0; t < 2; t++)
            vaddr[cg][t] = (cg * 16 + col) * 128 + (((t * 4 + quad) ^ (col & 7)) * 16);
#pragma unroll
    for (int t = 0; t < 2; t++)
        oaddr[t] = (128 + col) * 128 + (t * 4 + quad) * 16;

    f32x4 O[2][8], lacc[2];
#pragma unroll
    for (int ig = 0; ig < 2; ig++) {
#pragma unroll
        for (int cg = 0; cg < 8; cg++) O[ig][cg] = (f32x4){0.f, 0.f, 0.f, 0.f};
        lacc[ig] = (f32x4){0.f, 0.f, 0.f, 0.f};
    }

#pragma unroll 1
    for (int t8 = 0; t8 < 8; t8++) {
        const int jt = js * 8 + t8;
        const char* kg = Ks + (size_t)jt * 16384;
        const char* vg = Vs + (size_t)jt * 16384;
#pragma unroll
        for (int q = 0; q < 4; q++) {
            const int call = iw * 4 + q;
            GLD16(kg + call * 1024 + lane * 16, Kbytes + call * 1024 + lane * 16);
            GLD16(vg + call * 1024 + lane * 16, Vbytes + call * 1024 + lane * 16);
        }
        __syncthreads();

        // ---- S' = K.Q^T, accumulator pre-biased to -32 (exp2 offset) ----
        f32x4 S[2][4];
#pragma unroll
        for (int ig = 0; ig < 2; ig++)
#pragma unroll
            for (int jg = 0; jg < 4; jg++)
                S[ig][jg] = (f32x4){-32.f, -32.f, -32.f, -32.f};
#pragma unroll
        for (int ks = 0; ks < 4; ks++) {
            bf16x8 k0 = *(const bf16x8*)(Kbytes + kaddr[0][ks]);
            bf16x8 k1 = *(const bf16x8*)(Kbytes + kaddr[1][ks]);
            bf16x8 k2 = *(const bf16x8*)(Kbytes + kaddr[2][ks]);
            bf16x8 k3 = *(const bf16x8*)(Kbytes + kaddr[3][ks]);
            S[0][0] = MFMA16(k0, qf[0][ks], S[0][0]);
            S[1][0] = MFMA16(k0, qf[1][ks], S[1][0]);
            S[0][1] = MFMA16(k1, qf[0][ks], S[0][1]);
            S[1][1] = MFMA16(k1, qf[1][ks], S[1][1]);
            S[0][2] = MFMA16(k2, qf[0][ks], S[0][2]);
            S[1][2] = MFMA16(k2, qf[1][ks], S[1][2]);
            S[0][3] = MFMA16(k3, qf[0][ks], S[0][3]);
            S[1][3] = MFMA16(k3, qf[1][ks], S[1][3]);
        }

        // ---- P = exp2(S) ----
#pragma unroll
        for (int ig = 0; ig < 2; ig++)
#pragma unroll
            for (int jg = 0; jg < 4; jg++)
#pragma unroll
                for (int r = 0; r < 4; r++)
                    S[ig][jg][r] = __builtin_amdgcn_exp2f(S[ig][jg][r]);

        // ---- PV + l: lane-local P->B-frag pack by construction ----
#pragma unroll
        for (int t = 0; t < 2; t++) {
            bf16x8 pf0, pf1;
#pragma unroll
            for (int e = 0; e < 8; e++) {
                int jg = 2 * t + (e >> 2), r = e & 3;
                pf0[e] = (__bf16)S[0][jg][r];
                pf1[e] = (__bf16)S[1][jg][r];
            }
#pragma unroll
            for (int cg = 0; cg < 8; cg++) {
                bf16x8 vf = *(const bf16x8*)(Vbytes + vaddr[cg][t]);
                O[0][cg] = MFMA16(vf, pf0, O[0][cg]);
                O[1][cg] = MFMA16(vf, pf1, O[1][cg]);
            }
            bf16x8 of = *(const bf16x8*)(Vbytes + oaddr[t]);
            lacc[0] = MFMA16(of, pf0, lacc[0]);
            lacc[1] = MFMA16(of, pf1, lacc[1]);
        }
        __syncthreads();
    }

    // ---- epilogue: bf16 bounce [128 c][136] -> coalesced 32 KB plane ----
    __bf16* Ol = (__bf16*)smem;
#pragma unroll
    for (int ig = 0; ig < 2; ig++) {
#pragma unroll
        for (int cg = 0; cg < 8; cg++)
#pragma unroll
            for (int r = 0; r < 4; r++)
                Ol[(cg * 16 + quad * 4 + r) * 136 + iw * 32 + ig * 16 + col]
                    = (__bf16)O[ig][cg][r];
        if (quad == 0)
            Lpart[((size_t)b * 8 + js) * NN + i0 + iw * 32 + ig * 16 + col]
                = lacc[ig][0];
    }
    __syncthreads();
    {
        __bf16* Od = Opart + (((size_t)(b * 8 + js) * 32 + it) * CC) * 128;
#pragma unroll
        for (int e = 0; e < 8; e++) {
            int u = e * 256 + tid;            // 2048 x 16B chunks
            int c = u >> 4, ch = u & 15;
            *(uint4*)&Od[c * 128 + ch * 8] = *(const uint4*)&Ol[c * 136 + ch * 8];
        }
    }
}

// ---------------------------------------------------------------------------
// K3: merge 8 bf16 partials + residual + Wo GEMM -> out fp32, 32-n tiles.
// ---------------------------------------------------------------------------
__global__ __launch_bounds__(256, 2)
void proj_out(const __bf16* __restrict__ Opart, const float* __restrict__ Lpart,
              const float* __restrict__ x,
              const __bf16* __restrict__ Wpk, const float* __restrict__ bpk,
              const float* __restrict__ gamma, float* __restrict__ out)
{
    const int b    = blockIdx.y;
    const int n0   = blockIdx.x * 32;
    const int tid  = threadIdx.x;
    const int lane = tid & 63;
    const int wv   = __builtin_amdgcn_readfirstlane(tid >> 6);
    const int col  = lane & 15;
    const int quad = lane >> 4;

    __shared__ __bf16 sas[32 * 144];    // [n][c] bf16
    __shared__ float  outs[128 * 34];   // [o][n] fp32 bounce

    const float g = gamma[0];

    // ---- merge 8 partials + residual -> sa[n][c] bf16 in LDS ----
    {
        const int n  = tid & 31;
        const int c0 = tid >> 5;              // 0..7
        const int it = n0 >> 7;
        const int io = (n0 & 127) + n;
        float l = 0.f;
#pragma unroll
        for (int jsp = 0; jsp < 8; jsp++)
            l += Lpart[((size_t)b * 8 + jsp) * NN + n0 + n];
        const float gl = g / l;
        const float* xb = x + ((size_t)b * CC) * NN + n0 + n;
        const __bf16* Ob = Opart + (((size_t)(b * 8) * 32 + it) * CC) * 128;
#pragma unroll
        for (int i = 0; i < 8; i++) {
            int c = (c0 + i * 8) * 2;
            float s0 = 0.f, s1 = 0.f;
#pragma unroll
            for (int jsp = 0; jsp < 8; jsp++) {
                const __bf16* p = Ob + (size_t)jsp * (32 * CC * 128) + c * 128 + io;
                s0 += (float)p[0];
                s1 += (float)p[128];
            }
            float v0 = xb[(size_t)c * NN] + s0 * gl;
            float v1 = xb[(size_t)(c + 1) * NN] + s1 * gl;
            union { __bf16 h[2]; unsigned u; } pk;
            pk.h[0] = (__bf16)v0; pk.h[1] = (__bf16)v1;
            *(unsigned*)&sas[n * 144 + c] = pk.u;
        }
    }
    __syncthreads();

    bf16x8 Bf[2][4];
#pragma unroll
    for (int ng = 0; ng < 2; ng++)
#pragma unroll
        for (int ks = 0; ks < 4; ks++)
            Bf[ng][ks] = *(const bf16x8*)&sas[(ng * 16 + col) * 144 + ks * 32 + quad * 8];

#pragma unroll
    for (int p = 0; p < 2; p++) {
        const int pg = wv * 2 + p;
        const int o0 = pg * 16;
        bf16x8 Af[4];
#pragma unroll
        for (int ks = 0; ks < 4; ks++)
            Af[ks] = *(const bf16x8*)&Wpk[(((size_t)(3 * 8 + pg) * 4 + ks) * 64 + lane) * 8];

        f32x4 D[2];
#pragma unroll
        for (int ng = 0; ng < 2; ng++) D[ng] = (f32x4){0.f, 0.f, 0.f, 0.f};
#pragma unroll
        for (int ks = 0; ks < 4; ks++)
#pragma unroll
            for (int ng = 0; ng < 2; ng++)
                D[ng] = MFMA16(Af[ks], Bf[ng][ks], D[ng]);

        float4 bias = *(const float4*)(bpk + 3 * 128 + o0 + quad * 4);
#pragma unroll
        for (int ng = 0; ng < 2; ng++)
#pragma unroll
            for (int r = 0; r < 4; r++)
                outs[(o0 + quad * 4 + r) * 34 + ng * 16 + col]
                    = D[ng][r] + ((const float*)&bias)[r];
    }
    __syncthreads();

    // ---- coalesced writeout ----
    {
        float* od = out + ((size_t)b * CC) * NN + n0;
#pragma unroll
        for (int e = 0; e < 16; e++) {
            int k = e * 256 + tid;            // 4096 = 128 o x 32 n
            int o = k >> 5, n = k & 31;
            od[(size_t)o * NN + n] = outs[o * 34 + n];
        }
    }
}

// ---------------------------------------------------------------------------
extern "C" void kernel_launch(void* const* d_in, const int* in_sizes, int n_in,
                              void* d_out, int out_size, void* d_ws, size_t ws_size,
                              hipStream_t stream)
{
    const float* x  = (const float*)d_in[0];
    const float* Wq = (const float*)d_in[1];
    const float* bq = (const float*)d_in[2];
    const float* Wk = (const float*)d_in[3];
    const float* bk = (const float*)d_in[4];
    const float* Wv = (const float*)d_in[5];
    const float* bv = (const float*)d_in[6];
    const float* gm = (const float*)d_in[7];
    const float* Wo = (const float*)d_in[8];
    const float* bo = (const float*)d_in[9];

    __bf16* Qt    = (__bf16*)d_ws;                          // 4 MB
    __bf16* Kt    = Qt + (size_t)BB * NN * CC;              // 4 MB (swizzled)
    __bf16* Vblk  = Kt + (size_t)BB * NN * CC;              // 4 MB (blocked, swizzled)
    __bf16* Opart = Vblk + (size_t)BB * NN * CC;            // 32 planes bf16, 32 MB
    float*  Lpart = (float*)(Opart + (size_t)32 * 32 * CC * 128); // 512 KB
    __bf16* Wpk   = (__bf16*)(Lpart + (size_t)32 * NN);     // 128 KB packed frags
    float*  bpk   = (float*)(Wpk + 4 * 8 * 4 * 64 * 8);     // 2 KB biases
    float*  out   = (float*)d_out;

    pack_w<<<32, 256, 0, stream>>>(Wq, bq, Wk, bk, Wv, bv, Wo, bo, Wpk, bpk);
    qkv_gemm<<<dim3(128, 4), 512, 0, stream>>>(x, Wpk, bpk, Qt, Kt, Vblk);
    flash_attn<<<1024, 256, 0, stream>>>(Qt, Kt, Vblk, Opart, Lpart);
    proj_out<<<dim3(128, 4), 256, 0, stream>>>(Opart, Lpart, x, Wpk, bpk, gm, out);
}

// Round 9
// 127.590 us; speedup vs baseline: 1.5047x; 1.5047x over previous
//
#include <hip/hip_runtime.h>

#define BB 4
#define CC 128
#define NN 4096

typedef float f32x4 __attribute__((ext_vector_type(4)));
typedef __bf16 bf16x8 __attribute__((ext_vector_type(8)));

#define MFMA16(A, B, C) __builtin_amdgcn_mfma_f32_16x16x32_bf16((A), (B), (C), 0, 0, 0)

typedef __attribute__((address_space(3))) void lds_void;
typedef __attribute__((address_space(1))) void glob_void;
#define GLD16(g, l) __builtin_amdgcn_global_load_lds((const glob_void*)(g), (lds_void*)(l), 16, 0, 0)

// f(row): swizzle bits for 16B chunks within a 256B K row (16 chunks)
__device__ __forceinline__ int fK(int r) { return (r & 3) | (((r >> 3) & 1) << 2); }

// ---------------------------------------------------------------------------
// K0: one-shot weight prepack -> bf16 A-fragments, frag order
// [mat(4)][p(8)][ks(4)][lane(64)] x bf16x8. log2e folded into Wq/bq.
// (unchanged from R7)
// ---------------------------------------------------------------------------
__global__ __launch_bounds__(256)
void pack_w(const float* __restrict__ Wq, const float* __restrict__ bq,
            const float* __restrict__ Wk, const float* __restrict__ bk,
            const float* __restrict__ Wv, const float* __restrict__ bv,
            const float* __restrict__ Wo, const float* __restrict__ bo,
            __bf16* __restrict__ Wpk, float* __restrict__ bpk)
{
    const int mat = blockIdx.x >> 3;
    const int p   = blockIdx.x & 7;
    const int tid = threadIdx.x;
    const int ks  = tid >> 6;
    const int lane = tid & 63;
    const int col = lane & 15;
    const int quad = lane >> 4;

    const float LOG2E = 1.44269504088896340736f;
    const float* W = (mat == 0) ? Wq : (mat == 1) ? Wk : (mat == 2) ? Wv : Wo;
    const float* bsrc = (mat == 0) ? bq : (mat == 1) ? bk : (mat == 2) ? bv : bo;
    const float scale = (mat == 0) ? LOG2E : 1.0f;

    const float* wr = W + (size_t)(p * 16 + col) * CC + ks * 32 + quad * 8;
    float4 f0 = *(const float4*)wr;
    float4 f1 = *(const float4*)(wr + 4);
    bf16x8 a;
    a[0]=(__bf16)(f0.x*scale); a[1]=(__bf16)(f0.y*scale);
    a[2]=(__bf16)(f0.z*scale); a[3]=(__bf16)(f0.w*scale);
    a[4]=(__bf16)(f1.x*scale); a[5]=(__bf16)(f1.y*scale);
    a[6]=(__bf16)(f1.z*scale); a[7]=(__bf16)(f1.w*scale);
    *(bf16x8*)&Wpk[(((size_t)(mat * 8 + p) * 4 + ks) * 64 + lane) * 8] = a;

    if (p == 0 && tid < 128) bpk[mat * 128 + tid] = bsrc[tid] * scale;
}

// ---------------------------------------------------------------------------
// K1: QKV projection (unchanged from R7). 512-thr blocks, 32-n tiles, grid 512.
// ---------------------------------------------------------------------------
__global__ __launch_bounds__(512, 2)
void qkv_gemm(const float* __restrict__ x,
              const __bf16* __restrict__ Wpk, const float* __restrict__ bpk,
              __bf16* __restrict__ Qt, __bf16* __restrict__ Kt,
              __bf16* __restrict__ Vblk)
{
    const int b    = blockIdx.y;
    const int n0   = blockIdx.x * 32;
    const int tid  = threadIdx.x;
    const int lane = tid & 63;
    const int wv   = __builtin_amdgcn_readfirstlane(tid >> 6); // 0..7
    const int col  = lane & 15;
    const int quad = lane >> 4;

    __shared__ __bf16 xs[32 * 144];   // [n][c] bf16
    __shared__ __bf16 vs[128 * 32];   // V bounce [c][n]

    {
        const int n  = tid & 31;
        const int c0 = tid >> 5;               // 0..15
        const float* xb = x + ((size_t)b * CC) * NN + n0 + n;
#pragma unroll
        for (int i = 0; i < 4; i++) {
            int c = (c0 + i * 16) * 2;
            float v0 = xb[(size_t)c * NN];
            float v1 = xb[(size_t)(c + 1) * NN];
            union { __bf16 h[2]; unsigned u; } pk;
            pk.h[0] = (__bf16)v0; pk.h[1] = (__bf16)v1;
            *(unsigned*)&xs[n * 144 + c] = pk.u;
        }
    }
    __syncthreads();

    bf16x8 Bf[2][4];
#pragma unroll
    for (int ng = 0; ng < 2; ng++)
#pragma unroll
        for (int ks = 0; ks < 4; ks++)
            Bf[ng][ks] = *(const bf16x8*)&xs[(ng * 16 + col) * 144 + ks * 32 + quad * 8];

#pragma unroll 1
    for (int mat = 0; mat < 3; mat++) {           // 0=Q 1=K 2=V
        const int pg = wv;
        const int o0 = pg * 16;

        bf16x8 Af[4];
#pragma unroll
        for (int ks = 0; ks < 4; ks++)
            Af[ks] = *(const bf16x8*)&Wpk[(((size_t)(mat * 8 + pg) * 4 + ks) * 64 + lane) * 8];

        f32x4 D[2];
#pragma unroll
        for (int ng = 0; ng < 2; ng++) D[ng] = (f32x4){0.f, 0.f, 0.f, 0.f};
#pragma unroll
        for (int ks = 0; ks < 4; ks++)
#pragma unroll
            for (int ng = 0; ng < 2; ng++)
                D[ng] = MFMA16(Af[ks], Bf[ng][ks], D[ng]);

        float4 bias = *(const float4*)(bpk + mat * 128 + o0 + quad * 4);

#pragma unroll
        for (int ng = 0; ng < 2; ng++) {
            const int n = ng * 16 + col;              // tile-local 0..31
            float v[4];
#pragma unroll
            for (int r = 0; r < 4; r++)
                v[r] = D[ng][r] + ((const float*)&bias)[r];
            if (mat == 0) {
                union { __bf16 h[4]; uint2 u; } pk;
                for (int r = 0; r < 4; r++) pk.h[r] = (__bf16)v[r];
                *(uint2*)&Qt[((size_t)b * NN + n0 + n) * CC + o0 + quad * 4] = pk.u;
            } else if (mat == 1) {
                const int rin = ((n0 & 32) + n) & 63;       // row within 64-key tile
                const int chunk = ((o0 + quad * 4) >> 3) ^ fK(rin);
                union { __bf16 h[4]; uint2 u; } pk;
                for (int r = 0; r < 4; r++) pk.h[r] = (__bf16)v[r];
                *(uint2*)&Kt[((size_t)b * NN + n0 + n) * CC + chunk * 8 + (quad & 1) * 4] = pk.u;
            } else {
#pragma unroll
                for (int r = 0; r < 4; r++)
                    vs[(o0 + quad * 4 + r) * 32 + n] = (__bf16)v[r];
            }
        }
    }
    __syncthreads();

    {
        __bf16* vd = Vblk + (((size_t)b * 64 + (n0 >> 6)) * CC) * 64;
        const int chbase = (n0 & 32) >> 3;            // 0 or 4
        int idx = tid;                                // 0..511 = 128 c x 4 chunks
        int c = idx >> 2, chl = idx & 3;
        bf16x8 v = *(const bf16x8*)&vs[c * 32 + chl * 8];
        *(bf16x8*)&vd[c * 64 + (((chbase + chl) ^ (c & 7)) * 8)] = v;
    }
}

// ---------------------------------------------------------------------------
// K2: flash attention, R7 double-buffered structure (launch_bounds(256,2) —
// NEVER starve registers). Buffers shrunk to 2 x 32 KB (no ones-rows: l is
// computed by VALU lane-sums, quad-reduced once in the epilogue). Epilogue:
// bf16 LDS bounce -> fully-coalesced 32 KB plane to Opart[b][js][it][c][128].
// Grid 512: b=blk&3, jhi XCD-pinned; 4-way j-split, 16 tiles/block.
// ---------------------------------------------------------------------------
__global__ __launch_bounds__(256, 2)
void flash_attn(const __bf16* __restrict__ Qt, const __bf16* __restrict__ Kt,
                const __bf16* __restrict__ Vblk,
                __bf16* __restrict__ Opart, float* __restrict__ Lpart)
{
    const int blk = blockIdx.x;
    const int b   = blk & 3;                  // pinned per XCD
    const int jhi = (blk >> 2) & 1;           // pinned per XCD
    const int rr  = blk >> 3;                 // 0..63
    const int js  = jhi * 2 + (rr & 1);       // 0..3
    const int it  = rr >> 1;                  // 0..31
    const int i0  = it * 128;

    const int tid  = threadIdx.x;
    const int lane = tid & 63;
    const int iw   = __builtin_amdgcn_readfirstlane(tid >> 6); // 0..3
    const int col  = lane & 15;
    const int quad = lane >> 4;

    // two buffers: each K 16384 B + V 16384 B
    __shared__ __align__(16) char smem[65536];

    const __bf16* Qb = Qt + (size_t)b * NN * CC;
    const char*   Ks = (const char*)(Kt + (size_t)b * NN * CC);
    const char*   Vs = (const char*)(Vblk + ((size_t)b * 64 * CC) * 64);

    const int ibase = i0 + iw * 32;

    // Q fragments (B operand): n=col=query, k=quad*8+e
    bf16x8 qf[2][4];
#pragma unroll
    for (int ig = 0; ig < 2; ig++)
#pragma unroll
        for (int ks = 0; ks < 4; ks++)
            qf[ig][ks] = *(const bf16x8*)(Qb + (size_t)(ibase + ig * 16 + col) * CC
                                             + ks * 32 + quad * 8);

    // precomputed swizzled LDS byte addrs (buffer-relative)
    const int perm = ((col & 12) << 1) | (col & 3);
    const int fR   = fK(perm);
    int kaddr[4][4];
    const int joff[4] = {0, 4, 32, 36};
#pragma unroll
    for (int jg = 0; jg < 4; jg++)
#pragma unroll
        for (int ks = 0; ks < 4; ks++)
            kaddr[jg][ks] = (perm + joff[jg]) * 256 + (((ks * 4 + quad) ^ fR) * 16);
    int vaddr[8][2];
#pragma unroll
    for (int cg = 0; cg < 8; cg++)
#pragma unroll
        for (int t = 0; t < 2; t++)
            vaddr[cg][t] = 16384 + (cg * 16 + col) * 128 + (((t * 4 + quad) ^ (col & 7)) * 16);

    f32x4 O[2][8];
    float lrun[2] = {0.f, 0.f};
#pragma unroll
    for (int ig = 0; ig < 2; ig++)
#pragma unroll
        for (int cg = 0; cg < 8; cg++) O[ig][cg] = (f32x4){0.f, 0.f, 0.f, 0.f};

    // prestage tile 0 of this block's j-range into buffer 0
    {
        const char* kg = Ks + (size_t)(js * 16) * 16384;
        const char* vg = Vs + (size_t)(js * 16) * 16384;
#pragma unroll
        for (int q = 0; q < 4; q++) {
            const int call = iw * 4 + q;
            GLD16(kg + call * 1024 + lane * 16, smem + call * 1024 + lane * 16);
            GLD16(vg + call * 1024 + lane * 16, smem + 16384 + call * 1024 + lane * 16);
        }
    }

#pragma unroll 1
    for (int t16 = 0; t16 < 16; t16++) {
        __syncthreads();   // drains prefetch issued one full compute-phase ago

        char* Buf = smem + (t16 & 1) * 32768;

        if (t16 < 15) {    // prefetch next tile into the other buffer
            const int jt = js * 16 + t16 + 1;
            const char* kg = Ks + (size_t)jt * 16384;
            const char* vg = Vs + (size_t)jt * 16384;
            char* kd = smem + ((t16 + 1) & 1) * 32768;
#pragma unroll
            for (int q = 0; q < 4; q++) {
                const int call = iw * 4 + q;
                GLD16(kg + call * 1024 + lane * 16, kd + call * 1024 + lane * 16);
                GLD16(vg + call * 1024 + lane * 16, kd + 16384 + call * 1024 + lane * 16);
            }
        }

        // ---- S' = K.Q^T, accumulator pre-biased to -32 (exp2 offset) ----
        f32x4 S[2][4];
#pragma unroll
        for (int ig = 0; ig < 2; ig++)
#pragma unroll
            for (int jg = 0; jg < 4; jg++)
                S[ig][jg] = (f32x4){-32.f, -32.f, -32.f, -32.f};
#pragma unroll
        for (int ks = 0; ks < 4; ks++) {
            bf16x8 k0 = *(const bf16x8*)(Buf + kaddr[0][ks]);
            bf16x8 k1 = *(const bf16x8*)(Buf + kaddr[1][ks]);
            bf16x8 k2 = *(const bf16x8*)(Buf + kaddr[2][ks]);
            bf16x8 k3 = *(const bf16x8*)(Buf + kaddr[3][ks]);
            S[0][0] = MFMA16(k0, qf[0][ks], S[0][0]);
            S[1][0] = MFMA16(k0, qf[1][ks], S[1][0]);
            S[0][1] = MFMA16(k1, qf[0][ks], S[0][1]);
            S[1][1] = MFMA16(k1, qf[1][ks], S[1][1]);
            S[0][2] = MFMA16(k2, qf[0][ks], S[0][2]);
            S[1][2] = MFMA16(k2, qf[1][ks], S[1][2]);
            S[0][3] = MFMA16(k3, qf[0][ks], S[0][3]);
            S[1][3] = MFMA16(k3, qf[1][ks], S[1][3]);
        }

        // ---- P = exp2(S); accumulate lane-local l partials (VALU) ----
        float s0 = 0.f, s1 = 0.f;
#pragma unroll
        for (int jg = 0; jg < 4; jg++)
#pragma unroll
            for (int r = 0; r < 4; r++) {
                float p0 = __builtin_amdgcn_exp2f(S[0][jg][r]);
                float p1 = __builtin_amdgcn_exp2f(S[1][jg][r]);
                S[0][jg][r] = p0; s0 += p0;
                S[1][jg][r] = p1; s1 += p1;
            }
        lrun[0] += s0;
        lrun[1] += s1;

        // ---- PV: lane-local P->B-frag pack by construction ----
#pragma unroll
        for (int t = 0; t < 2; t++) {
            bf16x8 pf0, pf1;
#pragma unroll
            for (int e = 0; e < 8; e++) {
                int jg = 2 * t + (e >> 2), r = e & 3;
                pf0[e] = (__bf16)S[0][jg][r];
                pf1[e] = (__bf16)S[1][jg][r];
            }
#pragma unroll
            for (int cg = 0; cg < 8; cg++) {
                bf16x8 vf = *(const bf16x8*)(Buf + vaddr[cg][t]);
                O[0][cg] = MFMA16(vf, pf0, O[0][cg]);
                O[1][cg] = MFMA16(vf, pf1, O[1][cg]);
            }
        }
    }
    __syncthreads();

    // ---- epilogue: bf16 bounce [128 c][136] -> coalesced 32 KB plane ----
    __bf16* Ol = (__bf16*)smem;
#pragma unroll
    for (int ig = 0; ig < 2; ig++) {
        // quad-reduce l for this half's queries (cols) and store
        lrun[ig] += __shfl_xor(lrun[ig], 16);
        lrun[ig] += __shfl_xor(lrun[ig], 32);
#pragma unroll
        for (int cg = 0; cg < 8; cg++)
#pragma unroll
            for (int r = 0; r < 4; r++)
                Ol[(cg * 16 + quad * 4 + r) * 136 + iw * 32 + ig * 16 + col]
                    = (__bf16)O[ig][cg][r];
        if (quad == 0)
            Lpart[((size_t)b * 4 + js) * NN + i0 + iw * 32 + ig * 16 + col] = lrun[ig];
    }
    __syncthreads();
    {
        __bf16* Od = Opart + ((size_t)((b * 4 + js) * 32 + it) * CC) * 128;
#pragma unroll
        for (int e = 0; e < 8; e++) {
            int u = e * 256 + tid;            // 2048 x 16B chunks
            int c = u >> 4, ch = u & 15;
            *(uint4*)&Od[c * 128 + ch * 8] = *(const uint4*)&Ol[c * 136 + ch * 8];
        }
    }
}

// ---------------------------------------------------------------------------
// K3: merge 4 bf16 partials + residual + Wo GEMM -> out fp32, 32-n tiles.
// ---------------------------------------------------------------------------
__global__ __launch_bounds__(256, 2)
void proj_out(const __bf16* __restrict__ Opart, const float* __restrict__ Lpart,
              const float* __restrict__ x,
              const __bf16* __restrict__ Wpk, const float* __restrict__ bpk,
              const float* __restrict__ gamma, float* __restrict__ out)
{
    const int b    = blockIdx.y;
    const int n0   = blockIdx.x * 32;
    const int tid  = threadIdx.x;
    const int lane = tid & 63;
    const int wv   = __builtin_amdgcn_readfirstlane(tid >> 6);
    const int col  = lane & 15;
    const int quad = lane >> 4;

    __shared__ __bf16 sas[32 * 144];    // [n][c] bf16
    __shared__ float  outs[128 * 34];   // [o][n] fp32 bounce

    const float g = gamma[0];

    // ---- merge 4 partials + residual -> sa[n][c] bf16 in LDS ----
    {
        const int n  = tid & 31;
        const int c0 = tid >> 5;              // 0..7
        const int it = n0 >> 7;
        const int io = (n0 & 127) + n;
        float l = 0.f;
#pragma unroll
        for (int jsp = 0; jsp < 4; jsp++)
            l += Lpart[((size_t)b * 4 + jsp) * NN + n0 + n];
        const float gl = g / l;
        const float* xb = x + ((size_t)b * CC) * NN + n0 + n;
        const __bf16* Ob = Opart + ((size_t)(b * 4) * 32 + it) * CC * 128;
#pragma unroll
        for (int i = 0; i < 8; i++) {
            int c = (c0 + i * 8) * 2;
            float s0 = 0.f, s1 = 0.f;
#pragma unroll
            for (int jsp = 0; jsp < 4; jsp++) {
                const __bf16* p = Ob + (size_t)jsp * (32 * CC * 128) + c * 128 + io;
                s0 += (float)p[0];
                s1 += (float)p[128];
            }
            float v0 = xb[(size_t)c * NN] + s0 * gl;
            float v1 = xb[(size_t)(c + 1) * NN] + s1 * gl;
            union { __bf16 h[2]; unsigned u; } pk;
            pk.h[0] = (__bf16)v0; pk.h[1] = (__bf16)v1;
            *(unsigned*)&sas[n * 144 + c] = pk.u;
        }
    }
    __syncthreads();

    bf16x8 Bf[2][4];
#pragma unroll
    for (int ng = 0; ng < 2; ng++)
#pragma unroll
        for (int ks = 0; ks < 4; ks++)
            Bf[ng][ks] = *(const bf16x8*)&sas[(ng * 16 + col) * 144 + ks * 32 + quad * 8];

#pragma unroll
    for (int p = 0; p < 2; p++) {
        const int pg = wv * 2 + p;
        const int o0 = pg * 16;
        bf16x8 Af[4];
#pragma unroll
        for (int ks = 0; ks < 4; ks++)
            Af[ks] = *(const bf16x8*)&Wpk[(((size_t)(3 * 8 + pg) * 4 + ks) * 64 + lane) * 8];

        f32x4 D[2];
#pragma unroll
        for (int ng = 0; ng < 2; ng++) D[ng] = (f32x4){0.f, 0.f, 0.f, 0.f};
#pragma unroll
        for (int ks = 0; ks < 4; ks++)
#pragma unroll
            for (int ng = 0; ng < 2; ng++)
                D[ng] = MFMA16(Af[ks], Bf[ng][ks], D[ng]);

        float4 bias = *(const float4*)(bpk + 3 * 128 + o0 + quad * 4);
#pragma unroll
        for (int ng = 0; ng < 2; ng++)
#pragma unroll
            for (int r = 0; r < 4; r++)
                outs[(o0 + quad * 4 + r) * 34 + ng * 16 + col]
                    = D[ng][r] + ((const float*)&bias)[r];
    }
    __syncthreads();

    // ---- coalesced writeout ----
    {
        float* od = out + ((size_t)b * CC) * NN + n0;
#pragma unroll
        for (int e = 0; e < 16; e++) {
            int k = e * 256 + tid;            // 4096 = 128 o x 32 n
            int o = k >> 5, n = k & 31;
            od[(size_t)o * NN + n] = outs[o * 34 + n];
        }
    }
}

// ---------------------------------------------------------------------------
extern "C" void kernel_launch(void* const* d_in, const int* in_sizes, int n_in,
                              void* d_out, int out_size, void* d_ws, size_t ws_size,
                              hipStream_t stream)
{
    const float* x  = (const float*)d_in[0];
    const float* Wq = (const float*)d_in[1];
    const float* bq = (const float*)d_in[2];
    const float* Wk = (const float*)d_in[3];
    const float* bk = (const float*)d_in[4];
    const float* Wv = (const float*)d_in[5];
    const float* bv = (const float*)d_in[6];
    const float* gm = (const float*)d_in[7];
    const float* Wo = (const float*)d_in[8];
    const float* bo = (const float*)d_in[9];

    __bf16* Qt    = (__bf16*)d_ws;                          // 4 MB
    __bf16* Kt    = Qt + (size_t)BB * NN * CC;              // 4 MB (swizzled)
    __bf16* Vblk  = Kt + (size_t)BB * NN * CC;              // 4 MB (blocked, swizzled)
    __bf16* Opart = Vblk + (size_t)BB * NN * CC;            // 16 planes bf16, 16.8 MB
    float*  Lpart = (float*)(Opart + (size_t)16 * 32 * CC * 128); // 256 KB
    __bf16* Wpk   = (__bf16*)(Lpart + (size_t)16 * NN);     // 128 KB packed frags
    float*  bpk   = (float*)(Wpk + 4 * 8 * 4 * 64 * 8);     // 2 KB biases
    float*  out   = (float*)d_out;

    pack_w<<<32, 256, 0, stream>>>(Wq, bq, Wk, bk, Wv, bv, Wo, bo, Wpk, bpk);
    qkv_gemm<<<dim3(128, 4), 512, 0, stream>>>(x, Wpk, bpk, Qt, Kt, Vblk);
    flash_attn<<<512, 256, 0, stream>>>(Qt, Kt, Vblk, Opart, Lpart);
    proj_out<<<dim3(128, 4), 256, 0, stream>>>(Opart, Lpart, x, Wpk, bpk, gm, out);
}